// Round 5
// baseline (96.273 us; speedup 1.0000x reference)
//
#include <hip/hip_runtime.h>
#include <math.h>

// NeRF fused volume renderer, MI355X (gfx950) — MFMA, zero-shuffle chaining.
// Wave = ray, batch = 64 samples (2 batches for S=128), col lane&15 = sample.
// Round 5:
//   * L2/Wc/heads via mfma_f32_16x16x16f16 (K=16): D-frag rows (4g+reg) == next
//     B-frag k (4g+e)  ->  relu+pack IS the next layer's operand, no transposes.
//   * sigma head: A rows all = Ws -> D replicates sigma to every lane (3 selects).
//   * rgb head: A rows r = Wr[r%3] -> every lane holds all 3 colors (9 selects).
//   * launch_bounds(256,2): 256-VGPR cap, NO spills (r4 lesson: WRITE_SIZE is the tell).
// Layouts (m89-verified / ISA doc): C/D col=lane&15, row=(lane>>4)*4+reg;
// x32 A/B k=(lane>>4)*8+e; x16 A/B k=(lane>>4)*4+e.

typedef _Float16 f16x8 __attribute__((ext_vector_type(8)));
typedef _Float16 f16x4 __attribute__((ext_vector_type(4)));
typedef float f32x4 __attribute__((ext_vector_type(4)));

static constexpr float STEPf = 0.040594940802395566f; // 3*sqrt(3)/128 in f32

static __device__ __forceinline__ unsigned pk2(float a, float b) {
    return __builtin_bit_cast(unsigned, __builtin_amdgcn_cvt_pkrtz(a, b));
}
static __device__ __forceinline__ f16x8 mk8(unsigned a, unsigned b, unsigned c, unsigned d) {
    uint4 u = make_uint4(a, b, c, d);
    return __builtin_bit_cast(f16x8, u);
}
// relu + pack f32x4 -> f16x4 (the D->B handoff)
static __device__ __forceinline__ f16x4 pkh(const f32x4 c) {
    uint2 u;
    u.x = pk2(fmaxf(c[0], 0.f), fmaxf(c[1], 0.f));
    u.y = pk2(fmaxf(c[2], 0.f), fmaxf(c[3], 0.f));
    return __builtin_bit_cast(f16x4, u);
}

extern "C" __global__ void __launch_bounds__(256, 2)
nerf_mfma(const float* __restrict__ rays_o, const float* __restrict__ viewdirs,
          const void* __restrict__ occ,
          const float* __restrict__ W1g, const float* __restrict__ b1g,
          const float* __restrict__ W2g, const float* __restrict__ b2g,
          const float* __restrict__ Wsg, const float* __restrict__ bsg,
          const float* __restrict__ Wcg, const float* __restrict__ Wdg,
          const float* __restrict__ bcg, const float* __restrict__ Wrg,
          const float* __restrict__ brg,
          float* __restrict__ out, int nrays)
{
    // W1: K=32 A-frags (16B reads, granule16 swz). W2/Wc: K=16 A-frags (8B reads,
    // granule8 swz: addr = h*128 + ((gk ^ ((h&7)<<1))<<3) + (k&3)*2, gk=k>>2).
    __shared__ __align__(16) unsigned char sW1[64 * 64];
    __shared__ __align__(16) unsigned char sW2[64 * 128];
    __shared__ __align__(16) unsigned char sWc[64 * 128];
    __shared__ __align__(16) unsigned char sHC[16 * 128];  // rgb head: row r = Wr[.%3]
    __shared__ __align__(16) _Float16 sHS[64];             // sigma head row (broadcast)
    __shared__ __align__(16) float sB1[64], sB2[64];
    __shared__ __align__(16) float sPdB[4][64];
    __shared__ int sKind;

    const int tid = threadIdx.x;

    for (int idx = tid; idx < 64 * 32; idx += 256) {        // W1 (pad k>=27)
        const int h = idx >> 5, k = idx & 31;
        const float v = (k < 27) ? W1g[k * 64 + h] : 0.f;
        *(_Float16*)(sW1 + h * 64 + (((k >> 3) ^ (h & 3)) << 4) + ((k & 7) << 1)) = (_Float16)v;
    }
    for (int idx = tid; idx < 64 * 64; idx += 256) {        // W2, Wc (granule8 swz)
        const int h = idx >> 6, k = idx & 63;
        const int off = h * 128 + ((((k >> 2) ^ ((h & 7) << 1)) << 3)) + ((k & 3) << 1);
        *(_Float16*)(sW2 + off) = (_Float16)W2g[k * 64 + h];
        *(_Float16*)(sWc + off) = (_Float16)Wcg[k * 64 + h];
    }
    for (int idx = tid; idx < 16 * 64; idx += 256) {        // rgb head rows
        const int r = idx >> 6, k = idx & 63;
        const int off = r * 128 + ((((k >> 2) ^ ((r & 7) << 1)) << 3)) + ((k & 3) << 1);
        *(_Float16*)(sHC + off) = (_Float16)Wrg[k * 3 + (r % 3)];
    }
    if (tid < 64) {
        sB1[tid] = b1g[tid]; sB2[tid] = b2g[tid];
        sHS[tid] = (_Float16)Wsg[tid];
    }
    if (tid == 0) {   // sniff occ dtype: 0=u8, 1=i32, 2=f32
        const int*   oi = (const int*)occ;
        const float* of = (const float*)occ;
        bool i32ok = true, f32ok = true;
        for (int k = 0; k < 64; ++k) {
            if (oi[k] != 0 && oi[k] != 1) i32ok = false;
            const float f = of[k];
            if (!(f == 0.f || f == 1.f)) f32ok = false;
        }
        sKind = i32ok ? 1 : (f32ok ? 2 : 0);
    }
    __syncthreads();

    const int lane = tid & 63;
    const int wib  = tid >> 6;
    const int ray  = (blockIdx.x << 2) | wib;
    if (ray >= nrays) return;
    const int kind = sKind;
    const int lh = lane & 15, g = lane >> 4;
    const int swz8 = (lh & 7) << 1;                         // granule8 XOR key

    const float ox = rays_o[ray * 3 + 0], oy = rays_o[ray * 3 + 1], oz = rays_o[ray * 3 + 2];
    const float dxv = viewdirs[ray * 3 + 0], dyv = viewdirs[ray * 3 + 1], dzv = viewdirs[ray * 3 + 2];
    const float sdx = fabsf(dxv) < 1e-8f ? 1e-8f : dxv;
    const float sdy = fabsf(dyv) < 1e-8f ? 1e-8f : dyv;
    const float sdz = fabsf(dzv) < 1e-8f ? 1e-8f : dzv;
    const float t1x = (-1.5f - ox) / sdx, t2x = (1.5f - ox) / sdx;
    const float t1y = (-1.5f - oy) / sdy, t2y = (1.5f - oy) / sdy;
    const float t1z = (-1.5f - oz) / sdz, t2z = (1.5f - oz) / sdz;
    const float t_near = fmaxf(fmaxf(fminf(t1x, t2x), fminf(t1y, t2y)),
                               fmaxf(fminf(t1z, t2z), 0.f));
    const float t_far  = fminf(fminf(fmaxf(t1x, t2x), fmaxf(t1y, t2y)), fmaxf(t1z, t2z));

    // per-ray dir posenc -> sPdB[wib][j] = (pe_d @ Wd)[j] + bc[j]
    {
        float ped[15];
        ped[0] = dxv; ped[1] = dyv; ped[2] = dzv;
        const float dc[3] = {dxv, dyv, dzv};
        #pragma unroll
        for (int c = 0; c < 3; ++c) {
            float s1, c1;
            __sincosf(dc[c], &s1, &c1);
            ped[3 + c * 4 + 0] = s1;
            ped[3 + c * 4 + 1] = 2.f * s1 * c1;
            ped[3 + c * 4 + 2] = c1;
            ped[3 + c * 4 + 3] = 1.f - 2.f * s1 * s1;
        }
        float pd = 0.f;
        #pragma unroll
        for (int i = 0; i < 15; ++i) pd += ped[i] * Wdg[i * 64 + lane];
        sPdB[wib][lane] = pd + bcg[lane];
    }

    const float bsV = bsg[0];
    const float br0 = brg[0], br1 = brg[1], br2 = brg[2];

    // ---- prefetch per-batch own-sample validity + occupancy (both batches) ----
    bool inseg[2], valid[2];
    float tOwn[2];
    {
        int ci[2];
        bool inbox[2];
        #pragma unroll
        for (int b = 0; b < 2; ++b) {
            const float t = t_near + ((float)((b << 6) | lane) + 0.5f) * STEPf;
            tOwn[b] = t;
            inseg[b] = t < t_far;
            const float px = ox + dxv * t, py = oy + dyv * t, pz = oz + dzv * t;
            const float cx = (px + 1.5f) * (128.f / 3.f);
            const float cy = (py + 1.5f) * (128.f / 3.f);
            const float cz = (pz + 1.5f) * (128.f / 3.f);
            inbox[b] = (cx >= 0.f) & (cx < 128.f) & (cy >= 0.f) & (cy < 128.f)
                     & (cz >= 0.f) & (cz < 128.f);
            const int ix = min(max((int)floorf(cx), 0), 127);
            const int iy = min(max((int)floorf(cy), 0), 127);
            const int iz = min(max((int)floorf(cz), 0), 127);
            ci[b] = (ix << 14) | (iy << 7) | iz;
        }
        bool occv[2];
        if (kind == 1) {
            occv[0] = ((const int*)occ)[ci[0]] != 0; occv[1] = ((const int*)occ)[ci[1]] != 0;
        } else if (kind == 2) {
            occv[0] = ((const float*)occ)[ci[0]] != 0.f; occv[1] = ((const float*)occ)[ci[1]] != 0.f;
        } else {
            occv[0] = ((const unsigned char*)occ)[ci[0]] != 0;
            occv[1] = ((const unsigned char*)occ)[ci[1]] != 0;
        }
        valid[0] = inseg[0] & inbox[0] & occv[0];
        valid[1] = inseg[1] & inbox[1] & occv[1];
    }

    float carry = 0.f;
    float aW = 0.f, aWT = 0.f, aR = 0.f, aG = 0.f, aB = 0.f;

    #pragma unroll 1
    for (int b = 0; b < 2; ++b) {
        if (__ballot(inseg[b]) == 0ULL) break;

        if (__ballot(valid[b]) != 0ULL) {
            // ---- posenc directly in x32-B layout (lane: feats 8g..8g+7, samples 16nt+lh) ----
            f16x8 bx[4];
            #pragma unroll
            for (int nt = 0; nt < 4; ++nt) {
                const float ts = t_near + ((float)((b << 6) + (nt << 4) + lh) + 0.5f) * STEPf;
                const float qx = ox + dxv * ts, qy = oy + dyv * ts, qz = oz + dzv * ts;
                const float u = (g < 2) ? qx : ((g == 2) ? qy : qz);
                const float v = (g == 1) ? qy : ((g == 2) ? qz : 0.f);
                float su1, cu1, sv1, cv1;
                __sincosf(u, &su1, &cu1);
                __sincosf(v, &sv1, &cv1);
                const float su2 = 2.f * su1 * cu1, cu2 = 1.f - 2.f * su1 * su1;
                const float su4 = 2.f * su2 * cu2, cu4 = 1.f - 2.f * su2 * su2;
                const float su8 = 2.f * su4 * cu4, cu8 = 1.f - 2.f * su4 * su4;
                const float sv2 = 2.f * sv1 * cv1, cv2 = 1.f - 2.f * sv1 * sv1;
                const float sv4 = 2.f * sv2 * cv2, cv4 = 1.f - 2.f * sv2 * sv2;
                const float sv8 = 2.f * sv4 * cv4;
                const bool g0 = (g == 0);
                const float f0 = g0 ? qx : cu2;
                const float f1 = g0 ? qy : cu4;
                const float f2 = g0 ? qz : cu8;
                const float f3 = g0 ? su1 : sv1;
                const float f4 = g0 ? su2 : sv2;
                const float f5 = g0 ? su4 : sv4;
                const float f6 = g0 ? su8 : sv8;
                const float f7 = g0 ? cu1 : ((g == 3) ? 0.f : cv1);
                bx[nt] = mk8(pk2(f0, f1), pk2(f2, f3), pk2(f4, f5), pk2(f6, f7));
            }

            // ---- L1 (16x16x32): bias as C ----
            f16x4 bh1[4][4];
            {
                #pragma unroll
                for (int mt = 0; mt < 4; ++mt) {
                    const f32x4 bf = *(const f32x4*)&sB1[16 * mt + 4 * g];
                    const f16x8 a = *(const f16x8*)(sW1 + (16 * mt + lh) * 64 + ((g ^ (lh & 3)) << 4));
                    #pragma unroll
                    for (int nt = 0; nt < 4; ++nt) {
                        f32x4 c = __builtin_amdgcn_mfma_f32_16x16x32_f16(a, bx[nt], bf, 0, 0, 0);
                        bh1[mt][nt] = pkh(c);   // D rows 4g+r == B k 4g+e for k-step mt
                    }
                }
            }
            // ---- L2 (4 x 16x16x16 per tile): bias as C of ks=0 ----
            f16x4 bh2[4][4];
            {
                #pragma unroll
                for (int mt = 0; mt < 4; ++mt) {
                    const int row = (16 * mt + lh) * 128;
                    f16x4 a0 = *(const f16x4*)(sW2 + row + (((0 + g) ^ swz8) << 3));
                    f16x4 a1 = *(const f16x4*)(sW2 + row + (((4 + g) ^ swz8) << 3));
                    f16x4 a2 = *(const f16x4*)(sW2 + row + (((8 + g) ^ swz8) << 3));
                    f16x4 a3 = *(const f16x4*)(sW2 + row + (((12 + g) ^ swz8) << 3));
                    const f32x4 bf = *(const f32x4*)&sB2[16 * mt + 4 * g];
                    #pragma unroll
                    for (int nt = 0; nt < 4; ++nt) {
                        f32x4 c = __builtin_amdgcn_mfma_f32_16x16x16f16(a0, bh1[0][nt], bf, 0, 0, 0);
                        c = __builtin_amdgcn_mfma_f32_16x16x16f16(a1, bh1[1][nt], c, 0, 0, 0);
                        c = __builtin_amdgcn_mfma_f32_16x16x16f16(a2, bh1[2][nt], c, 0, 0, 0);
                        c = __builtin_amdgcn_mfma_f32_16x16x16f16(a3, bh1[3][nt], c, 0, 0, 0);
                        bh2[mt][nt] = pkh(c);
                    }
                }
            }
            // ---- sigma head: A rows all = Ws -> D replicates sigma over rows ----
            f32x4 accS[4];
            {
                f16x4 aS[4];
                #pragma unroll
                for (int ks = 0; ks < 4; ++ks)
                    aS[ks] = *(const f16x4*)(sHS + 16 * ks + 4 * g);
                #pragma unroll
                for (int nt = 0; nt < 4; ++nt) {
                    f32x4 c = {0.f, 0.f, 0.f, 0.f};
                    c = __builtin_amdgcn_mfma_f32_16x16x16f16(aS[0], bh2[0][nt], c, 0, 0, 0);
                    c = __builtin_amdgcn_mfma_f32_16x16x16f16(aS[1], bh2[1][nt], c, 0, 0, 0);
                    c = __builtin_amdgcn_mfma_f32_16x16x16f16(aS[2], bh2[2][nt], c, 0, 0, 0);
                    c = __builtin_amdgcn_mfma_f32_16x16x16f16(aS[3], bh2[3][nt], c, 0, 0, 0);
                    accS[nt] = c;
                }
            }
            // ---- Wc layer (C = pd + bc) ----
            f16x4 bg[4][4];
            {
                #pragma unroll
                for (int mt = 0; mt < 4; ++mt) {
                    const int row = (16 * mt + lh) * 128;
                    f16x4 a0 = *(const f16x4*)(sWc + row + (((0 + g) ^ swz8) << 3));
                    f16x4 a1 = *(const f16x4*)(sWc + row + (((4 + g) ^ swz8) << 3));
                    f16x4 a2 = *(const f16x4*)(sWc + row + (((8 + g) ^ swz8) << 3));
                    f16x4 a3 = *(const f16x4*)(sWc + row + (((12 + g) ^ swz8) << 3));
                    const f32x4 pdf = *(const f32x4*)&sPdB[wib][16 * mt + 4 * g];
                    #pragma unroll
                    for (int nt = 0; nt < 4; ++nt) {
                        f32x4 c = __builtin_amdgcn_mfma_f32_16x16x16f16(a0, bh2[0][nt], pdf, 0, 0, 0);
                        c = __builtin_amdgcn_mfma_f32_16x16x16f16(a1, bh2[1][nt], c, 0, 0, 0);
                        c = __builtin_amdgcn_mfma_f32_16x16x16f16(a2, bh2[2][nt], c, 0, 0, 0);
                        c = __builtin_amdgcn_mfma_f32_16x16x16f16(a3, bh2[3][nt], c, 0, 0, 0);
                        bg[mt][nt] = pkh(c);
                    }
                }
            }
            // ---- rgb head: A row r = Wr[r%3] -> every lane holds all 3 colors ----
            f32x4 accC[4];
            {
                #pragma unroll
                for (int ks = 0; ks < 4; ++ks) {
                    const f16x4 aC = *(const f16x4*)(sHC + lh * 128 + (((4 * ks + g) ^ swz8) << 3));
                    #pragma unroll
                    for (int nt = 0; nt < 4; ++nt) {
                        f32x4 c = (ks == 0) ? f32x4{0.f, 0.f, 0.f, 0.f} : accC[nt];
                        accC[nt] = __builtin_amdgcn_mfma_f32_16x16x16f16(aC, bh2[ks][nt], c, 0, 0, 0);
                    }
                }
                // overwrite: accC must use bg (color features), not bh2 — redo correctly
            }
            {
                #pragma unroll
                for (int ks = 0; ks < 4; ++ks) {
                    const f16x4 aC = *(const f16x4*)(sHC + lh * 128 + (((4 * ks + g) ^ swz8) << 3));
                    #pragma unroll
                    for (int nt = 0; nt < 4; ++nt) {
                        f32x4 c = (ks == 0) ? f32x4{0.f, 0.f, 0.f, 0.f} : accC[nt];
                        accC[nt] = __builtin_amdgcn_mfma_f32_16x16x16f16(aC, bg[ks][nt], c, 0, 0, 0);
                    }
                }
            }
            // ---- own-sample extraction (nt == g), reg (c-g+3)%3 for color c ----
            const float sraw = (g == 0) ? accS[0][0] : (g == 1) ? accS[1][0]
                             : (g == 2) ? accS[2][0] : accS[3][0];
            const float crS  = (g == 0) ? accC[0][0] : (g == 1) ? accC[1][2]
                             : (g == 2) ? accC[2][1] : accC[3][0];
            const float cgS  = (g == 0) ? accC[0][1] : (g == 1) ? accC[1][0]
                             : (g == 2) ? accC[2][2] : accC[3][1];
            const float cbS  = (g == 0) ? accC[0][2] : (g == 1) ? accC[1][1]
                             : (g == 2) ? accC[2][0] : accC[3][2];

            const float sigma = valid[b] ? fmaxf(sraw + bsV, 0.f) : 0.f;
            const float rC = 1.f / (1.f + __expf(-(crS + br0)));
            const float gC = 1.f / (1.f + __expf(-(cgS + br1)));
            const float bC = 1.f / (1.f + __expf(-(cbS + br2)));

            // ---- compositing: wave inclusive scan ----
            const float sdelta = sigma * STEPf;
            float scan = sdelta;
            #pragma unroll
            for (int off = 1; off < 64; off <<= 1) {
                const float n = __shfl_up(scan, off);
                if (lane >= off) scan += n;
            }
            const float T     = __expf(-(carry + scan - sdelta));
            const float alpha = 1.f - __expf(-sdelta);
            const float w = T * alpha;
            aW  += w;
            aWT += w * tOwn[b];
            aR  += w * rC;
            aG  += w * gC;
            aB  += w * bC;
            carry += __shfl(scan, 63);
            if (carry > 12.f) break;
        }
    }

    // ---- reduce across lanes + store ----
    #pragma unroll
    for (int off = 32; off; off >>= 1) {
        aW  += __shfl_xor(aW,  off);
        aWT += __shfl_xor(aWT, off);
        aR  += __shfl_xor(aR,  off);
        aG  += __shfl_xor(aG,  off);
        aB  += __shfl_xor(aB,  off);
    }
    if (lane == 0) {
        const float bg_ = 1.f - aW;
        out[ray * 3 + 0] = aR + bg_;
        out[ray * 3 + 1] = aG + bg_;
        out[ray * 3 + 2] = aB + bg_;
        out[3 * nrays + ray] = aWT;
        out[4 * nrays + ray] = aW;
    }
}

extern "C" void kernel_launch(void* const* d_in, const int* in_sizes, int n_in,
                              void* d_out, int out_size, void* d_ws, size_t ws_size,
                              hipStream_t stream) {
    const float* rays_o   = (const float*)d_in[0];
    const float* viewdirs = (const float*)d_in[1];
    const void*  occ      = (const void*) d_in[2];
    const float* W1 = (const float*)d_in[3];
    const float* b1 = (const float*)d_in[4];
    const float* W2 = (const float*)d_in[5];
    const float* b2 = (const float*)d_in[6];
    const float* Ws = (const float*)d_in[7];
    const float* bs = (const float*)d_in[8];
    const float* Wc = (const float*)d_in[9];
    const float* Wd = (const float*)d_in[10];
    const float* bc = (const float*)d_in[11];
    const float* Wr = (const float*)d_in[12];
    const float* br = (const float*)d_in[13];
    float* out = (float*)d_out;

    const int nrays = in_sizes[0] / 3;
    const int nblocks = (nrays + 3) / 4;   // 4 rays (waves) per 256-thread block

    nerf_mfma<<<nblocks, 256, 0, stream>>>(rays_o, viewdirs, occ,
                                           W1, b1, W2, b2, Ws, bs, Wc, Wd, bc, Wr, br,
                                           out, nrays);
}

// Round 6
// 72.701 us; speedup vs baseline: 1.3242x; 1.3242x over previous
//
#include <hip/hip_runtime.h>
#include <math.h>

// NeRF fused volume renderer, MI355X (gfx950) — MFMA, zero-shuffle chaining.
// Round 6: staging fix + persistent blocks.
//   * Weight staging reads are COALESCED (linear idx over the global array,
//     swizzled scatter on the LDS write side). r3-r5's uncoalesced reads
//     (stride-256B per lane -> 64 cache lines per wave load) were the floor.
//   * Persistent grid (768 blocks, 3/CU): each wave grid-strides over rays;
//     staging paid 768x instead of 2048x, amortized over ~10.7 rays/block.
//   * Compute structure = round 5 (passed, absmax 7.8e-3): L1 via 16x16x32,
//     L2/Wc/heads via 16x16x16 (D rows 4g+r == next B k 4g+e -> no transposes),
//     sigma/rgb heads as MFMA with broadcast/replicated A rows.
// Layouts (m89-verified / ISA doc): C/D col=lane&15, row=(lane>>4)*4+reg;
// x32 A/B k=(lane>>4)*8+e; x16 A/B k=(lane>>4)*4+e.

typedef _Float16 f16x8 __attribute__((ext_vector_type(8)));
typedef _Float16 f16x4 __attribute__((ext_vector_type(4)));
typedef float f32x4 __attribute__((ext_vector_type(4)));

static constexpr float STEPf = 0.040594940802395566f; // 3*sqrt(3)/128 in f32

static __device__ __forceinline__ unsigned pk2(float a, float b) {
    return __builtin_bit_cast(unsigned, __builtin_amdgcn_cvt_pkrtz(a, b));
}
static __device__ __forceinline__ f16x8 mk8(unsigned a, unsigned b, unsigned c, unsigned d) {
    uint4 u = make_uint4(a, b, c, d);
    return __builtin_bit_cast(f16x8, u);
}
// relu + pack f32x4 -> f16x4 (the D->B handoff)
static __device__ __forceinline__ f16x4 pkh(const f32x4 c) {
    uint2 u;
    u.x = pk2(fmaxf(c[0], 0.f), fmaxf(c[1], 0.f));
    u.y = pk2(fmaxf(c[2], 0.f), fmaxf(c[3], 0.f));
    return __builtin_bit_cast(f16x4, u);
}

extern "C" __global__ void __launch_bounds__(256, 2)
nerf_mfma(const float* __restrict__ rays_o, const float* __restrict__ viewdirs,
          const void* __restrict__ occ,
          const float* __restrict__ W1g, const float* __restrict__ b1g,
          const float* __restrict__ W2g, const float* __restrict__ b2g,
          const float* __restrict__ Wsg, const float* __restrict__ bsg,
          const float* __restrict__ Wcg, const float* __restrict__ Wdg,
          const float* __restrict__ bcg, const float* __restrict__ Wrg,
          const float* __restrict__ brg,
          float* __restrict__ out, int nrays)
{
    // W1: K=32 A-frags (16B reads, granule16 swz). W2/Wc: K=16 A-frags (8B reads,
    // granule8 swz). sHC: rgb head, row r = Wr[.][r%3].
    __shared__ __align__(16) unsigned char sW1[64 * 64];
    __shared__ __align__(16) unsigned char sW2[64 * 128];
    __shared__ __align__(16) unsigned char sWc[64 * 128];
    __shared__ __align__(16) unsigned char sHC[16 * 128];
    __shared__ __align__(16) _Float16 sHS[64];
    __shared__ __align__(16) float sB1[64], sB2[64];
    __shared__ __align__(16) float sPdB[4][64];
    __shared__ int sKind;

    const int tid = threadIdx.x;

    // ---------------- staging: COALESCED global reads, swizzled LDS writes ----
    for (int idx = tid; idx < 1024; idx += 256)             // zero sW1 (covers k-pad)
        ((uint32_t*)sW1)[idx] = 0u;
    __syncthreads();                                        // pad-zero before scatter
    for (int idx = tid; idx < 27 * 64; idx += 256) {        // W1, linear in memory
        const int k = idx >> 6, h = idx & 63;
        *(_Float16*)(sW1 + h * 64 + (((k >> 3) ^ (h & 3)) << 4) + ((k & 7) << 1)) =
            (_Float16)W1g[idx];
    }
    for (int idx = tid; idx < 64 * 64; idx += 256) {        // W2, Wc, linear
        const int k = idx >> 6, h = idx & 63;
        const int off = h * 128 + ((((k >> 2) ^ ((h & 7) << 1)) << 3)) + ((k & 3) << 1);
        *(_Float16*)(sW2 + off) = (_Float16)W2g[idx];
        *(_Float16*)(sWc + off) = (_Float16)Wcg[idx];
    }
    for (int idx = tid; idx < 192; idx += 256) {            // rgb head rows, linear
        const int kk = idx / 3, c = idx - 3 * kk;
        const _Float16 v = (_Float16)Wrg[idx];
        #pragma unroll
        for (int r = 0; r < 16; ++r) {
            if ((r % 3) == c) {
                const int off = r * 128 + ((((kk >> 2) ^ ((r & 7) << 1)) << 3)) + ((kk & 3) << 1);
                *(_Float16*)(sHC + off) = v;
            }
        }
    }
    if (tid < 64) {
        sB1[tid] = b1g[tid]; sB2[tid] = b2g[tid];
        sHS[tid] = (_Float16)Wsg[tid];
    }
    if (tid == 0) {   // sniff occ dtype: 0=u8, 1=i32, 2=f32
        const int*   oi = (const int*)occ;
        const float* of = (const float*)occ;
        bool i32ok = true, f32ok = true;
        for (int k = 0; k < 64; ++k) {
            if (oi[k] != 0 && oi[k] != 1) i32ok = false;
            const float f = of[k];
            if (!(f == 0.f || f == 1.f)) f32ok = false;
        }
        sKind = i32ok ? 1 : (f32ok ? 2 : 0);
    }
    __syncthreads();

    const int lane = tid & 63;
    const int wib  = tid >> 6;
    const int kind = sKind;
    const int lh = lane & 15, g = lane >> 4;
    const int swz8 = (lh & 7) << 1;
    const int rayStride = (int)(gridDim.x << 2);

    const float bsV = bsg[0];
    const float br0 = brg[0], br1 = brg[1], br2 = brg[2];

    for (int ray = (int)(blockIdx.x << 2) | wib; ray < nrays; ray += rayStride) {

        const float ox = rays_o[ray * 3 + 0], oy = rays_o[ray * 3 + 1], oz = rays_o[ray * 3 + 2];
        const float dxv = viewdirs[ray * 3 + 0], dyv = viewdirs[ray * 3 + 1], dzv = viewdirs[ray * 3 + 2];
        const float sdx = fabsf(dxv) < 1e-8f ? 1e-8f : dxv;
        const float sdy = fabsf(dyv) < 1e-8f ? 1e-8f : dyv;
        const float sdz = fabsf(dzv) < 1e-8f ? 1e-8f : dzv;
        const float t1x = (-1.5f - ox) / sdx, t2x = (1.5f - ox) / sdx;
        const float t1y = (-1.5f - oy) / sdy, t2y = (1.5f - oy) / sdy;
        const float t1z = (-1.5f - oz) / sdz, t2z = (1.5f - oz) / sdz;
        const float t_near = fmaxf(fmaxf(fminf(t1x, t2x), fminf(t1y, t2y)),
                                   fmaxf(fminf(t1z, t2z), 0.f));
        const float t_far  = fminf(fminf(fmaxf(t1x, t2x), fmaxf(t1y, t2y)), fmaxf(t1z, t2z));

        // per-ray dir posenc -> sPdB[wib][j] = (pe_d @ Wd)[j] + bc[j]
        {
            float ped[15];
            ped[0] = dxv; ped[1] = dyv; ped[2] = dzv;
            const float dc[3] = {dxv, dyv, dzv};
            #pragma unroll
            for (int c = 0; c < 3; ++c) {
                float s1, c1;
                __sincosf(dc[c], &s1, &c1);
                ped[3 + c * 4 + 0] = s1;
                ped[3 + c * 4 + 1] = 2.f * s1 * c1;
                ped[3 + c * 4 + 2] = c1;
                ped[3 + c * 4 + 3] = 1.f - 2.f * s1 * s1;
            }
            float pd = 0.f;
            #pragma unroll
            for (int i = 0; i < 15; ++i) pd += ped[i] * Wdg[i * 64 + lane];
            sPdB[wib][lane] = pd + bcg[lane];
        }

        // ---- prefetch per-batch own-sample validity + occupancy ----
        bool inseg[2], valid[2];
        float tOwn[2];
        {
            int ci[2];
            bool inbox[2];
            #pragma unroll
            for (int b = 0; b < 2; ++b) {
                const float t = t_near + ((float)((b << 6) | lane) + 0.5f) * STEPf;
                tOwn[b] = t;
                inseg[b] = t < t_far;
                const float px = ox + dxv * t, py = oy + dyv * t, pz = oz + dzv * t;
                const float cx = (px + 1.5f) * (128.f / 3.f);
                const float cy = (py + 1.5f) * (128.f / 3.f);
                const float cz = (pz + 1.5f) * (128.f / 3.f);
                inbox[b] = (cx >= 0.f) & (cx < 128.f) & (cy >= 0.f) & (cy < 128.f)
                         & (cz >= 0.f) & (cz < 128.f);
                const int ix = min(max((int)floorf(cx), 0), 127);
                const int iy = min(max((int)floorf(cy), 0), 127);
                const int iz = min(max((int)floorf(cz), 0), 127);
                ci[b] = (ix << 14) | (iy << 7) | iz;
            }
            bool occv[2];
            if (kind == 1) {
                occv[0] = ((const int*)occ)[ci[0]] != 0; occv[1] = ((const int*)occ)[ci[1]] != 0;
            } else if (kind == 2) {
                occv[0] = ((const float*)occ)[ci[0]] != 0.f; occv[1] = ((const float*)occ)[ci[1]] != 0.f;
            } else {
                occv[0] = ((const unsigned char*)occ)[ci[0]] != 0;
                occv[1] = ((const unsigned char*)occ)[ci[1]] != 0;
            }
            valid[0] = inseg[0] & inbox[0] & occv[0];
            valid[1] = inseg[1] & inbox[1] & occv[1];
        }

        float carry = 0.f;
        float aW = 0.f, aWT = 0.f, aR = 0.f, aG = 0.f, aB = 0.f;

        #pragma unroll 1
        for (int b = 0; b < 2; ++b) {
            if (__ballot(inseg[b]) == 0ULL) break;

            if (__ballot(valid[b]) != 0ULL) {
                // ---- posenc in x32-B layout (lane: feats 8g..8g+7, samples 16nt+lh) ----
                f16x8 bx[4];
                #pragma unroll
                for (int nt = 0; nt < 4; ++nt) {
                    const float ts = t_near + ((float)((b << 6) + (nt << 4) + lh) + 0.5f) * STEPf;
                    const float qx = ox + dxv * ts, qy = oy + dyv * ts, qz = oz + dzv * ts;
                    const float u = (g < 2) ? qx : ((g == 2) ? qy : qz);
                    const float v = (g == 1) ? qy : ((g == 2) ? qz : 0.f);
                    float su1, cu1, sv1, cv1;
                    __sincosf(u, &su1, &cu1);
                    __sincosf(v, &sv1, &cv1);
                    const float su2 = 2.f * su1 * cu1, cu2 = 1.f - 2.f * su1 * su1;
                    const float su4 = 2.f * su2 * cu2, cu4 = 1.f - 2.f * su2 * su2;
                    const float su8 = 2.f * su4 * cu4, cu8 = 1.f - 2.f * su4 * su4;
                    const float sv2 = 2.f * sv1 * cv1, cv2 = 1.f - 2.f * sv1 * sv1;
                    const float sv4 = 2.f * sv2 * cv2, cv4 = 1.f - 2.f * sv2 * sv2;
                    const float sv8 = 2.f * sv4 * cv4;
                    const bool g0 = (g == 0);
                    const float f0 = g0 ? qx : cu2;
                    const float f1 = g0 ? qy : cu4;
                    const float f2 = g0 ? qz : cu8;
                    const float f3 = g0 ? su1 : sv1;
                    const float f4 = g0 ? su2 : sv2;
                    const float f5 = g0 ? su4 : sv4;
                    const float f6 = g0 ? su8 : sv8;
                    const float f7 = g0 ? cu1 : ((g == 3) ? 0.f : cv1);
                    bx[nt] = mk8(pk2(f0, f1), pk2(f2, f3), pk2(f4, f5), pk2(f6, f7));
                }

                // ---- L1 (16x16x32): bias as C ----
                f16x4 bh1[4][4];
                #pragma unroll
                for (int mt = 0; mt < 4; ++mt) {
                    const f32x4 bf = *(const f32x4*)&sB1[16 * mt + 4 * g];
                    const f16x8 a = *(const f16x8*)(sW1 + (16 * mt + lh) * 64 + ((g ^ (lh & 3)) << 4));
                    #pragma unroll
                    for (int nt = 0; nt < 4; ++nt) {
                        f32x4 c = __builtin_amdgcn_mfma_f32_16x16x32_f16(a, bx[nt], bf, 0, 0, 0);
                        bh1[mt][nt] = pkh(c);   // D rows 4g+r == B k 4g+e for k-step mt
                    }
                }
                // ---- L2 (4 x 16x16x16 per tile) ----
                f16x4 bh2[4][4];
                #pragma unroll
                for (int mt = 0; mt < 4; ++mt) {
                    const int row = (16 * mt + lh) * 128;
                    f16x4 a0 = *(const f16x4*)(sW2 + row + (((0 + g) ^ swz8) << 3));
                    f16x4 a1 = *(const f16x4*)(sW2 + row + (((4 + g) ^ swz8) << 3));
                    f16x4 a2 = *(const f16x4*)(sW2 + row + (((8 + g) ^ swz8) << 3));
                    f16x4 a3 = *(const f16x4*)(sW2 + row + (((12 + g) ^ swz8) << 3));
                    const f32x4 bf = *(const f32x4*)&sB2[16 * mt + 4 * g];
                    #pragma unroll
                    for (int nt = 0; nt < 4; ++nt) {
                        f32x4 c = __builtin_amdgcn_mfma_f32_16x16x16f16(a0, bh1[0][nt], bf, 0, 0, 0);
                        c = __builtin_amdgcn_mfma_f32_16x16x16f16(a1, bh1[1][nt], c, 0, 0, 0);
                        c = __builtin_amdgcn_mfma_f32_16x16x16f16(a2, bh1[2][nt], c, 0, 0, 0);
                        c = __builtin_amdgcn_mfma_f32_16x16x16f16(a3, bh1[3][nt], c, 0, 0, 0);
                        bh2[mt][nt] = pkh(c);
                    }
                }
                // ---- sigma head: A rows all = Ws -> D replicates sigma over rows ----
                f32x4 accS[4];
                {
                    f16x4 aS[4];
                    #pragma unroll
                    for (int ks = 0; ks < 4; ++ks)
                        aS[ks] = *(const f16x4*)(sHS + 16 * ks + 4 * g);
                    #pragma unroll
                    for (int nt = 0; nt < 4; ++nt) {
                        f32x4 c = {0.f, 0.f, 0.f, 0.f};
                        c = __builtin_amdgcn_mfma_f32_16x16x16f16(aS[0], bh2[0][nt], c, 0, 0, 0);
                        c = __builtin_amdgcn_mfma_f32_16x16x16f16(aS[1], bh2[1][nt], c, 0, 0, 0);
                        c = __builtin_amdgcn_mfma_f32_16x16x16f16(aS[2], bh2[2][nt], c, 0, 0, 0);
                        c = __builtin_amdgcn_mfma_f32_16x16x16f16(aS[3], bh2[3][nt], c, 0, 0, 0);
                        accS[nt] = c;
                    }
                }
                // ---- Wc layer (C = pd + bc) ----
                f16x4 bgf[4][4];
                #pragma unroll
                for (int mt = 0; mt < 4; ++mt) {
                    const int row = (16 * mt + lh) * 128;
                    f16x4 a0 = *(const f16x4*)(sWc + row + (((0 + g) ^ swz8) << 3));
                    f16x4 a1 = *(const f16x4*)(sWc + row + (((4 + g) ^ swz8) << 3));
                    f16x4 a2 = *(const f16x4*)(sWc + row + (((8 + g) ^ swz8) << 3));
                    f16x4 a3 = *(const f16x4*)(sWc + row + (((12 + g) ^ swz8) << 3));
                    const f32x4 pdf = *(const f32x4*)&sPdB[wib][16 * mt + 4 * g];
                    #pragma unroll
                    for (int nt = 0; nt < 4; ++nt) {
                        f32x4 c = __builtin_amdgcn_mfma_f32_16x16x16f16(a0, bh2[0][nt], pdf, 0, 0, 0);
                        c = __builtin_amdgcn_mfma_f32_16x16x16f16(a1, bh2[1][nt], c, 0, 0, 0);
                        c = __builtin_amdgcn_mfma_f32_16x16x16f16(a2, bh2[2][nt], c, 0, 0, 0);
                        c = __builtin_amdgcn_mfma_f32_16x16x16f16(a3, bh2[3][nt], c, 0, 0, 0);
                        bgf[mt][nt] = pkh(c);
                    }
                }
                // ---- rgb head: A row r = Wr[.][r%3] -> every lane holds all 3 colors ----
                f32x4 accC[4];
                #pragma unroll
                for (int ks = 0; ks < 4; ++ks) {
                    const f16x4 aC = *(const f16x4*)(sHC + lh * 128 + (((4 * ks + g) ^ swz8) << 3));
                    #pragma unroll
                    for (int nt = 0; nt < 4; ++nt) {
                        f32x4 c = (ks == 0) ? f32x4{0.f, 0.f, 0.f, 0.f} : accC[nt];
                        accC[nt] = __builtin_amdgcn_mfma_f32_16x16x16f16(aC, bgf[ks][nt], c, 0, 0, 0);
                    }
                }
                // ---- own-sample extraction (nt == g), reg (c-g+3)%3 for color c ----
                const float sraw = (g == 0) ? accS[0][0] : (g == 1) ? accS[1][0]
                                 : (g == 2) ? accS[2][0] : accS[3][0];
                const float crS  = (g == 0) ? accC[0][0] : (g == 1) ? accC[1][2]
                                 : (g == 2) ? accC[2][1] : accC[3][0];
                const float cgS  = (g == 0) ? accC[0][1] : (g == 1) ? accC[1][0]
                                 : (g == 2) ? accC[2][2] : accC[3][1];
                const float cbS  = (g == 0) ? accC[0][2] : (g == 1) ? accC[1][1]
                                 : (g == 2) ? accC[2][0] : accC[3][2];

                const float sigma = valid[b] ? fmaxf(sraw + bsV, 0.f) : 0.f;
                const float rC = 1.f / (1.f + __expf(-(crS + br0)));
                const float gC = 1.f / (1.f + __expf(-(cgS + br1)));
                const float bC = 1.f / (1.f + __expf(-(cbS + br2)));

                // ---- compositing: wave inclusive scan ----
                const float sdelta = sigma * STEPf;
                float scan = sdelta;
                #pragma unroll
                for (int off = 1; off < 64; off <<= 1) {
                    const float n = __shfl_up(scan, off);
                    if (lane >= off) scan += n;
                }
                const float T     = __expf(-(carry + scan - sdelta));
                const float alpha = 1.f - __expf(-sdelta);
                const float w = T * alpha;
                aW  += w;
                aWT += w * tOwn[b];
                aR  += w * rC;
                aG  += w * gC;
                aB  += w * bC;
                carry += __shfl(scan, 63);
                if (carry > 12.f) break;
            }
        }

        // ---- reduce across lanes + store ----
        #pragma unroll
        for (int off = 32; off; off >>= 1) {
            aW  += __shfl_xor(aW,  off);
            aWT += __shfl_xor(aWT, off);
            aR  += __shfl_xor(aR,  off);
            aG  += __shfl_xor(aG,  off);
            aB  += __shfl_xor(aB,  off);
        }
        if (lane == 0) {
            const float bg_ = 1.f - aW;
            out[ray * 3 + 0] = aR + bg_;
            out[ray * 3 + 1] = aG + bg_;
            out[ray * 3 + 2] = aB + bg_;
            out[3 * nrays + ray] = aWT;
            out[4 * nrays + ray] = aW;
        }
    }
}

extern "C" void kernel_launch(void* const* d_in, const int* in_sizes, int n_in,
                              void* d_out, int out_size, void* d_ws, size_t ws_size,
                              hipStream_t stream) {
    const float* rays_o   = (const float*)d_in[0];
    const float* viewdirs = (const float*)d_in[1];
    const void*  occ      = (const void*) d_in[2];
    const float* W1 = (const float*)d_in[3];
    const float* b1 = (const float*)d_in[4];
    const float* W2 = (const float*)d_in[5];
    const float* b2 = (const float*)d_in[6];
    const float* Ws = (const float*)d_in[7];
    const float* bs = (const float*)d_in[8];
    const float* Wc = (const float*)d_in[9];
    const float* Wd = (const float*)d_in[10];
    const float* bc = (const float*)d_in[11];
    const float* Wr = (const float*)d_in[12];
    const float* br = (const float*)d_in[13];
    float* out = (float*)d_out;

    const int nrays = in_sizes[0] / 3;
    int nblocks = 768;                       // persistent: 3 blocks/CU, grid-stride
    const int needed = (nrays + 3) / 4;
    if (needed < nblocks) nblocks = needed;

    nerf_mfma<<<nblocks, 256, 0, stream>>>(rays_o, viewdirs, occ,
                                           W1, b1, W2, b2, Ws, bs, Wc, Wd, bc, Wr, br,
                                           out, nrays);
}

// Round 7
// 54.162 us; speedup vs baseline: 1.7775x; 1.3423x over previous
//
#include <hip/hip_runtime.h>
#include <math.h>

// NeRF fused volume renderer, MI355X (gfx950) — MFMA, wave-parallel batches.
// Round 7: wave = (ray, 64-sample batch): 2 waves per ray, 2 rays per block.
//   The only inter-batch dependency is the transmittance carry, which factors
//   as exp(-S0) multiplying all of batch 1's composited weights:
//     P_total = P_batch0 + exp(-S0) * P_batch1   (exact)
//   so both batches' MLPs run fully in parallel; combine = 6-float LDS exchange.
//   Per-ray critical path halves; wave count doubles (8192 -> 16384).
//   Grid 1024 persistent (4 blocks/CU), launch_bounds(256,4).
// Compute structure = round 5/6 (passed, absmax 7.8e-3): L1 via 16x16x32,
// L2/Wc/heads via 16x16x16 zero-shuffle chaining; coalesced staging (r6).
// Layouts (m89-verified / ISA doc): C/D col=lane&15, row=(lane>>4)*4+reg;
// x32 A/B k=(lane>>4)*8+e; x16 A/B k=(lane>>4)*4+e.

typedef _Float16 f16x8 __attribute__((ext_vector_type(8)));
typedef _Float16 f16x4 __attribute__((ext_vector_type(4)));
typedef float f32x4 __attribute__((ext_vector_type(4)));

static constexpr float STEPf = 0.040594940802395566f; // 3*sqrt(3)/128 in f32

static __device__ __forceinline__ unsigned pk2(float a, float b) {
    return __builtin_bit_cast(unsigned, __builtin_amdgcn_cvt_pkrtz(a, b));
}
static __device__ __forceinline__ f16x8 mk8(unsigned a, unsigned b, unsigned c, unsigned d) {
    uint4 u = make_uint4(a, b, c, d);
    return __builtin_bit_cast(f16x8, u);
}
// relu + pack f32x4 -> f16x4 (the D->B handoff)
static __device__ __forceinline__ f16x4 pkh(const f32x4 c) {
    uint2 u;
    u.x = pk2(fmaxf(c[0], 0.f), fmaxf(c[1], 0.f));
    u.y = pk2(fmaxf(c[2], 0.f), fmaxf(c[3], 0.f));
    return __builtin_bit_cast(f16x4, u);
}

extern "C" __global__ void __launch_bounds__(256, 4)
nerf_mfma(const float* __restrict__ rays_o, const float* __restrict__ viewdirs,
          const void* __restrict__ occ,
          const float* __restrict__ W1g, const float* __restrict__ b1g,
          const float* __restrict__ W2g, const float* __restrict__ b2g,
          const float* __restrict__ Wsg, const float* __restrict__ bsg,
          const float* __restrict__ Wcg, const float* __restrict__ Wdg,
          const float* __restrict__ bcg, const float* __restrict__ Wrg,
          const float* __restrict__ brg,
          float* __restrict__ out, int nrays)
{
    __shared__ __align__(16) unsigned char sW1[64 * 64];
    __shared__ __align__(16) unsigned char sW2[64 * 128];
    __shared__ __align__(16) unsigned char sWc[64 * 128];
    __shared__ __align__(16) unsigned char sHC[16 * 128];
    __shared__ __align__(16) _Float16 sHS[64];
    __shared__ __align__(16) float sB1[64], sB2[64];
    __shared__ __align__(16) float sPdB[4][64];
    __shared__ __align__(16) float sRed[4][6];    // per-wave {aW,aWT,aR,aG,aB,S}
    __shared__ int sKind;

    const int tid = threadIdx.x;

    // ---------------- staging: COALESCED global reads, swizzled LDS writes ----
    for (int idx = tid; idx < 1024; idx += 256)             // zero sW1 (covers k-pad)
        ((uint32_t*)sW1)[idx] = 0u;
    __syncthreads();                                        // pad-zero before scatter
    for (int idx = tid; idx < 27 * 64; idx += 256) {        // W1, linear in memory
        const int k = idx >> 6, h = idx & 63;
        *(_Float16*)(sW1 + h * 64 + (((k >> 3) ^ (h & 3)) << 4) + ((k & 7) << 1)) =
            (_Float16)W1g[idx];
    }
    for (int idx = tid; idx < 64 * 64; idx += 256) {        // W2, Wc, linear
        const int k = idx >> 6, h = idx & 63;
        const int off = h * 128 + ((((k >> 2) ^ ((h & 7) << 1)) << 3)) + ((k & 3) << 1);
        *(_Float16*)(sW2 + off) = (_Float16)W2g[idx];
        *(_Float16*)(sWc + off) = (_Float16)Wcg[idx];
    }
    for (int idx = tid; idx < 192; idx += 256) {            // rgb head rows, linear
        const int kk = idx / 3, c = idx - 3 * kk;
        const _Float16 v = (_Float16)Wrg[idx];
        #pragma unroll
        for (int r = 0; r < 16; ++r) {
            if ((r % 3) == c) {
                const int off = r * 128 + ((((kk >> 2) ^ ((r & 7) << 1)) << 3)) + ((kk & 3) << 1);
                *(_Float16*)(sHC + off) = v;
            }
        }
    }
    if (tid < 64) {
        sB1[tid] = b1g[tid]; sB2[tid] = b2g[tid];
        sHS[tid] = (_Float16)Wsg[tid];
    }
    if (tid == 0) {   // sniff occ dtype: 0=u8, 1=i32, 2=f32
        const int*   oi = (const int*)occ;
        const float* of = (const float*)occ;
        bool i32ok = true, f32ok = true;
        for (int k = 0; k < 64; ++k) {
            if (oi[k] != 0 && oi[k] != 1) i32ok = false;
            const float f = of[k];
            if (!(f == 0.f || f == 1.f)) f32ok = false;
        }
        sKind = i32ok ? 1 : (f32ok ? 2 : 0);
    }
    __syncthreads();

    const int lane = tid & 63;
    const int wid  = tid >> 6;
    const int bat  = wid & 1;         // batch this wave owns
    const int pr   = wid >> 1;        // ray slot within block (0/1)
    const int kind = sKind;
    const int lh = lane & 15, g = lane >> 4;
    const int swz8 = (lh & 7) << 1;

    const float bsV = bsg[0];
    const float br0 = brg[0], br1 = brg[1], br2 = brg[2];

    const int baseStride = (int)(gridDim.x << 1);
    for (int base = (int)(blockIdx.x << 1); base < nrays; base += baseStride) {
        const int ray = base + pr;
        const bool haveRay = ray < nrays;

        float aW = 0.f, aWT = 0.f, aR = 0.f, aG = 0.f, aB = 0.f, Ssum = 0.f;

        if (haveRay) {
            const float ox = rays_o[ray * 3 + 0], oy = rays_o[ray * 3 + 1], oz = rays_o[ray * 3 + 2];
            const float dxv = viewdirs[ray * 3 + 0], dyv = viewdirs[ray * 3 + 1], dzv = viewdirs[ray * 3 + 2];
            const float sdx = fabsf(dxv) < 1e-8f ? 1e-8f : dxv;
            const float sdy = fabsf(dyv) < 1e-8f ? 1e-8f : dyv;
            const float sdz = fabsf(dzv) < 1e-8f ? 1e-8f : dzv;
            const float t1x = (-1.5f - ox) / sdx, t2x = (1.5f - ox) / sdx;
            const float t1y = (-1.5f - oy) / sdy, t2y = (1.5f - oy) / sdy;
            const float t1z = (-1.5f - oz) / sdz, t2z = (1.5f - oz) / sdz;
            const float t_near = fmaxf(fmaxf(fminf(t1x, t2x), fminf(t1y, t2y)),
                                       fmaxf(fminf(t1z, t2z), 0.f));
            const float t_far  = fminf(fminf(fmaxf(t1x, t2x), fmaxf(t1y, t2y)), fmaxf(t1z, t2z));

            // per-ray dir posenc -> sPdB[wid][j] (each wave computes its own copy)
            {
                float ped[15];
                ped[0] = dxv; ped[1] = dyv; ped[2] = dzv;
                const float dc[3] = {dxv, dyv, dzv};
                #pragma unroll
                for (int c = 0; c < 3; ++c) {
                    float s1, c1;
                    __sincosf(dc[c], &s1, &c1);
                    ped[3 + c * 4 + 0] = s1;
                    ped[3 + c * 4 + 1] = 2.f * s1 * c1;
                    ped[3 + c * 4 + 2] = c1;
                    ped[3 + c * 4 + 3] = 1.f - 2.f * s1 * s1;
                }
                float pd = 0.f;
                #pragma unroll
                for (int i = 0; i < 15; ++i) pd += ped[i] * Wdg[i * 64 + lane];
                sPdB[wid][lane] = pd + bcg[lane];
            }

            // ---- own-sample validity + occupancy gather ----
            const float tS = t_near + ((float)((bat << 6) | lane) + 0.5f) * STEPf;
            const bool in_seg = tS < t_far;
            bool valid;
            {
                const float px = ox + dxv * tS, py = oy + dyv * tS, pz = oz + dzv * tS;
                const float cx = (px + 1.5f) * (128.f / 3.f);
                const float cy = (py + 1.5f) * (128.f / 3.f);
                const float cz = (pz + 1.5f) * (128.f / 3.f);
                const bool in_box = (cx >= 0.f) & (cx < 128.f) & (cy >= 0.f) & (cy < 128.f)
                                  & (cz >= 0.f) & (cz < 128.f);
                const int ix = min(max((int)floorf(cx), 0), 127);
                const int iy = min(max((int)floorf(cy), 0), 127);
                const int iz = min(max((int)floorf(cz), 0), 127);
                const int ci = (ix << 14) | (iy << 7) | iz;
                bool occv;
                if (kind == 1)      occv = ((const int*)occ)[ci] != 0;
                else if (kind == 2) occv = ((const float*)occ)[ci] != 0.f;
                else                occv = ((const unsigned char*)occ)[ci] != 0;
                valid = in_seg & in_box & occv;
            }

            if (__ballot(valid) != 0ULL) {
                // ---- posenc in x32-B layout (lane: feats 8g..8g+7, samples 16nt+lh) ----
                f16x8 bx[4];
                #pragma unroll
                for (int nt = 0; nt < 4; ++nt) {
                    const float ts = t_near + ((float)((bat << 6) + (nt << 4) + lh) + 0.5f) * STEPf;
                    const float qx = ox + dxv * ts, qy = oy + dyv * ts, qz = oz + dzv * ts;
                    const float u = (g < 2) ? qx : ((g == 2) ? qy : qz);
                    const float v = (g == 1) ? qy : ((g == 2) ? qz : 0.f);
                    float su1, cu1, sv1, cv1;
                    __sincosf(u, &su1, &cu1);
                    __sincosf(v, &sv1, &cv1);
                    const float su2 = 2.f * su1 * cu1, cu2 = 1.f - 2.f * su1 * su1;
                    const float su4 = 2.f * su2 * cu2, cu4 = 1.f - 2.f * su2 * su2;
                    const float su8 = 2.f * su4 * cu4, cu8 = 1.f - 2.f * su4 * su4;
                    const float sv2 = 2.f * sv1 * cv1, cv2 = 1.f - 2.f * sv1 * sv1;
                    const float sv4 = 2.f * sv2 * cv2, cv4 = 1.f - 2.f * sv2 * sv2;
                    const float sv8 = 2.f * sv4 * cv4;
                    const bool g0 = (g == 0);
                    const float f0 = g0 ? qx : cu2;
                    const float f1 = g0 ? qy : cu4;
                    const float f2 = g0 ? qz : cu8;
                    const float f3 = g0 ? su1 : sv1;
                    const float f4 = g0 ? su2 : sv2;
                    const float f5 = g0 ? su4 : sv4;
                    const float f6 = g0 ? su8 : sv8;
                    const float f7 = g0 ? cu1 : ((g == 3) ? 0.f : cv1);
                    bx[nt] = mk8(pk2(f0, f1), pk2(f2, f3), pk2(f4, f5), pk2(f6, f7));
                }

                // ---- L1 (16x16x32): bias as C ----
                f16x4 bh1[4][4];
                #pragma unroll
                for (int mt = 0; mt < 4; ++mt) {
                    const f32x4 bf = *(const f32x4*)&sB1[16 * mt + 4 * g];
                    const f16x8 a = *(const f16x8*)(sW1 + (16 * mt + lh) * 64 + ((g ^ (lh & 3)) << 4));
                    #pragma unroll
                    for (int nt = 0; nt < 4; ++nt) {
                        f32x4 c = __builtin_amdgcn_mfma_f32_16x16x32_f16(a, bx[nt], bf, 0, 0, 0);
                        bh1[mt][nt] = pkh(c);   // D rows 4g+r == B k 4g+e for k-step mt
                    }
                }
                // ---- L2 (4 x 16x16x16 per tile) ----
                f16x4 bh2[4][4];
                #pragma unroll
                for (int mt = 0; mt < 4; ++mt) {
                    const int row = (16 * mt + lh) * 128;
                    f16x4 a0 = *(const f16x4*)(sW2 + row + (((0 + g) ^ swz8) << 3));
                    f16x4 a1 = *(const f16x4*)(sW2 + row + (((4 + g) ^ swz8) << 3));
                    f16x4 a2 = *(const f16x4*)(sW2 + row + (((8 + g) ^ swz8) << 3));
                    f16x4 a3 = *(const f16x4*)(sW2 + row + (((12 + g) ^ swz8) << 3));
                    const f32x4 bf = *(const f32x4*)&sB2[16 * mt + 4 * g];
                    #pragma unroll
                    for (int nt = 0; nt < 4; ++nt) {
                        f32x4 c = __builtin_amdgcn_mfma_f32_16x16x16f16(a0, bh1[0][nt], bf, 0, 0, 0);
                        c = __builtin_amdgcn_mfma_f32_16x16x16f16(a1, bh1[1][nt], c, 0, 0, 0);
                        c = __builtin_amdgcn_mfma_f32_16x16x16f16(a2, bh1[2][nt], c, 0, 0, 0);
                        c = __builtin_amdgcn_mfma_f32_16x16x16f16(a3, bh1[3][nt], c, 0, 0, 0);
                        bh2[mt][nt] = pkh(c);
                    }
                }
                // ---- sigma head: A rows all = Ws -> D replicates sigma over rows ----
                f32x4 accS[4];
                {
                    f16x4 aS[4];
                    #pragma unroll
                    for (int ks = 0; ks < 4; ++ks)
                        aS[ks] = *(const f16x4*)(sHS + 16 * ks + 4 * g);
                    #pragma unroll
                    for (int nt = 0; nt < 4; ++nt) {
                        f32x4 c = {0.f, 0.f, 0.f, 0.f};
                        c = __builtin_amdgcn_mfma_f32_16x16x16f16(aS[0], bh2[0][nt], c, 0, 0, 0);
                        c = __builtin_amdgcn_mfma_f32_16x16x16f16(aS[1], bh2[1][nt], c, 0, 0, 0);
                        c = __builtin_amdgcn_mfma_f32_16x16x16f16(aS[2], bh2[2][nt], c, 0, 0, 0);
                        c = __builtin_amdgcn_mfma_f32_16x16x16f16(aS[3], bh2[3][nt], c, 0, 0, 0);
                        accS[nt] = c;
                    }
                }
                // ---- Wc layer (C = pd + bc) ----
                f16x4 bgf[4][4];
                #pragma unroll
                for (int mt = 0; mt < 4; ++mt) {
                    const int row = (16 * mt + lh) * 128;
                    f16x4 a0 = *(const f16x4*)(sWc + row + (((0 + g) ^ swz8) << 3));
                    f16x4 a1 = *(const f16x4*)(sWc + row + (((4 + g) ^ swz8) << 3));
                    f16x4 a2 = *(const f16x4*)(sWc + row + (((8 + g) ^ swz8) << 3));
                    f16x4 a3 = *(const f16x4*)(sWc + row + (((12 + g) ^ swz8) << 3));
                    const f32x4 pdf = *(const f32x4*)&sPdB[wid][16 * mt + 4 * g];
                    #pragma unroll
                    for (int nt = 0; nt < 4; ++nt) {
                        f32x4 c = __builtin_amdgcn_mfma_f32_16x16x16f16(a0, bh2[0][nt], pdf, 0, 0, 0);
                        c = __builtin_amdgcn_mfma_f32_16x16x16f16(a1, bh2[1][nt], c, 0, 0, 0);
                        c = __builtin_amdgcn_mfma_f32_16x16x16f16(a2, bh2[2][nt], c, 0, 0, 0);
                        c = __builtin_amdgcn_mfma_f32_16x16x16f16(a3, bh2[3][nt], c, 0, 0, 0);
                        bgf[mt][nt] = pkh(c);
                    }
                }
                // ---- rgb head: A row r = Wr[.][r%3] -> every lane holds all 3 colors ----
                f32x4 accC[4];
                #pragma unroll
                for (int ks = 0; ks < 4; ++ks) {
                    const f16x4 aC = *(const f16x4*)(sHC + lh * 128 + (((4 * ks + g) ^ swz8) << 3));
                    #pragma unroll
                    for (int nt = 0; nt < 4; ++nt) {
                        f32x4 c = (ks == 0) ? f32x4{0.f, 0.f, 0.f, 0.f} : accC[nt];
                        accC[nt] = __builtin_amdgcn_mfma_f32_16x16x16f16(aC, bgf[ks][nt], c, 0, 0, 0);
                    }
                }
                // ---- own-sample extraction (nt == g), reg (c-g+3)%3 for color c ----
                const float sraw = (g == 0) ? accS[0][0] : (g == 1) ? accS[1][0]
                                 : (g == 2) ? accS[2][0] : accS[3][0];
                const float crS  = (g == 0) ? accC[0][0] : (g == 1) ? accC[1][2]
                                 : (g == 2) ? accC[2][1] : accC[3][0];
                const float cgS  = (g == 0) ? accC[0][1] : (g == 1) ? accC[1][0]
                                 : (g == 2) ? accC[2][2] : accC[3][1];
                const float cbS  = (g == 0) ? accC[0][2] : (g == 1) ? accC[1][1]
                                 : (g == 2) ? accC[2][0] : accC[3][2];

                const float sigma = valid ? fmaxf(sraw + bsV, 0.f) : 0.f;
                const float rC = 1.f / (1.f + __expf(-(crS + br0)));
                const float gC = 1.f / (1.f + __expf(-(cgS + br1)));
                const float bC = 1.f / (1.f + __expf(-(cbS + br2)));

                // ---- compositing with carry = 0 (exact factoring: see header) ----
                const float sdelta = sigma * STEPf;
                float scan = sdelta;
                #pragma unroll
                for (int off = 1; off < 64; off <<= 1) {
                    const float n = __shfl_up(scan, off);
                    if (lane >= off) scan += n;
                }
                const float T     = __expf(-(scan - sdelta));
                const float alpha = 1.f - __expf(-sdelta);
                const float w = T * alpha;
                aW  = w;
                aWT = w * tS;
                aR  = w * rC;
                aG  = w * gC;
                aB  = w * bC;
                Ssum = __shfl(scan, 63);
            }
        }

        // ---- wave-reduce the five accumulators (all lanes end with totals) ----
        #pragma unroll
        for (int off = 32; off; off >>= 1) {
            aW  += __shfl_xor(aW,  off);
            aWT += __shfl_xor(aWT, off);
            aR  += __shfl_xor(aR,  off);
            aG  += __shfl_xor(aG,  off);
            aB  += __shfl_xor(aB,  off);
        }
        if (lane == 0) {
            sRed[wid][0] = aW;  sRed[wid][1] = aWT; sRed[wid][2] = aR;
            sRed[wid][3] = aG;  sRed[wid][4] = aB;  sRed[wid][5] = Ssum;
        }
        __syncthreads();
        if (haveRay && bat == 0 && lane == 0) {
            const float f = __expf(-Ssum);           // exp(-S0): batch-1 scale
            const float W1a = aW  + f * sRed[wid | 1][0];
            const float WTa = aWT + f * sRed[wid | 1][1];
            const float Ra  = aR  + f * sRed[wid | 1][2];
            const float Ga  = aG  + f * sRed[wid | 1][3];
            const float Ba  = aB  + f * sRed[wid | 1][4];
            const float bg_ = 1.f - W1a;
            out[ray * 3 + 0] = Ra + bg_;
            out[ray * 3 + 1] = Ga + bg_;
            out[ray * 3 + 2] = Ba + bg_;
            out[3 * nrays + ray] = WTa;
            out[4 * nrays + ray] = W1a;
        }
        __syncthreads();   // protect sRed/sPdB reuse next iteration
    }
}

extern "C" void kernel_launch(void* const* d_in, const int* in_sizes, int n_in,
                              void* d_out, int out_size, void* d_ws, size_t ws_size,
                              hipStream_t stream) {
    const float* rays_o   = (const float*)d_in[0];
    const float* viewdirs = (const float*)d_in[1];
    const void*  occ      = (const void*) d_in[2];
    const float* W1 = (const float*)d_in[3];
    const float* b1 = (const float*)d_in[4];
    const float* W2 = (const float*)d_in[5];
    const float* b2 = (const float*)d_in[6];
    const float* Ws = (const float*)d_in[7];
    const float* bs = (const float*)d_in[8];
    const float* Wc = (const float*)d_in[9];
    const float* Wd = (const float*)d_in[10];
    const float* bc = (const float*)d_in[11];
    const float* Wr = (const float*)d_in[12];
    const float* br = (const float*)d_in[13];
    float* out = (float*)d_out;

    const int nrays = in_sizes[0] / 3;
    int nblocks = 1024;                      // persistent: 4 blocks/CU, grid-stride
    const int needed = (nrays + 1) / 2;      // 2 rays per block
    if (needed < nblocks) nblocks = needed;

    nerf_mfma<<<nblocks, 256, 0, stream>>>(rays_o, viewdirs, occ,
                                           W1, b1, W2, b2, Ws, bs, Wc, Wd, bc, Wr, br,
                                           out, nrays);
}

// Round 8
// 53.512 us; speedup vs baseline: 1.7991x; 1.0121x over previous
//
#include <hip/hip_runtime.h>
#include <math.h>

// NeRF fused volume renderer, MI355X (gfx950) — MFMA, wave-parallel batches.
// Round 8: r7 structure minus the spill.
//   * r7's accS (sigma head via MFMA, 16 live VGPR) pushed peak pressure to ~130
//     > the 128-VGPR cap of launch_bounds(256,4) -> 12.7MB/dispatch scratch.
//   * Sigma head is now VALU partials sp[4] fused into the L2 relu/pack loop
//     (4 VGPR), reduced with 8 shfl_xor + g-select (validated r3/r4 pattern).
//     Peak live ~95 VGPR -> fits 128, no spill, occupancy stays 4 blocks/CU.
//   * Batch factoring (exact): P_total = P_b0 + exp(-S0) * P_b1.
// Layouts (m89-verified / ISA doc): C/D col=lane&15, row=(lane>>4)*4+reg;
// x32 A/B k=(lane>>4)*8+e; x16 A/B k=(lane>>4)*4+e.

typedef _Float16 f16x8 __attribute__((ext_vector_type(8)));
typedef _Float16 f16x4 __attribute__((ext_vector_type(4)));
typedef float f32x4 __attribute__((ext_vector_type(4)));

static constexpr float STEPf = 0.040594940802395566f; // 3*sqrt(3)/128 in f32

static __device__ __forceinline__ unsigned pk2(float a, float b) {
    return __builtin_bit_cast(unsigned, __builtin_amdgcn_cvt_pkrtz(a, b));
}
static __device__ __forceinline__ f16x8 mk8(unsigned a, unsigned b, unsigned c, unsigned d) {
    uint4 u = make_uint4(a, b, c, d);
    return __builtin_bit_cast(f16x8, u);
}
static __device__ __forceinline__ f16x4 pkh(const f32x4 c) {
    uint2 u;
    u.x = pk2(fmaxf(c[0], 0.f), fmaxf(c[1], 0.f));
    u.y = pk2(fmaxf(c[2], 0.f), fmaxf(c[3], 0.f));
    return __builtin_bit_cast(f16x4, u);
}

extern "C" __global__ void __launch_bounds__(256, 4)
nerf_mfma(const float* __restrict__ rays_o, const float* __restrict__ viewdirs,
          const void* __restrict__ occ,
          const float* __restrict__ W1g, const float* __restrict__ b1g,
          const float* __restrict__ W2g, const float* __restrict__ b2g,
          const float* __restrict__ Wsg, const float* __restrict__ bsg,
          const float* __restrict__ Wcg, const float* __restrict__ Wdg,
          const float* __restrict__ bcg, const float* __restrict__ Wrg,
          const float* __restrict__ brg,
          float* __restrict__ out, int nrays)
{
    __shared__ __align__(16) unsigned char sW1[64 * 64];
    __shared__ __align__(16) unsigned char sW2[64 * 128];
    __shared__ __align__(16) unsigned char sWc[64 * 128];
    __shared__ __align__(16) unsigned char sHC[16 * 128];
    __shared__ __align__(16) float sWs[64];
    __shared__ __align__(16) float sB1[64], sB2[64];
    __shared__ __align__(16) float sPdB[4][64];
    __shared__ __align__(16) float sRed[4][6];    // per-wave {aW,aWT,aR,aG,aB,S}
    __shared__ int sKind;

    const int tid = threadIdx.x;

    // ---------------- staging: COALESCED global reads, swizzled LDS writes ----
    for (int idx = tid; idx < 1024; idx += 256)             // zero sW1 (covers k-pad)
        ((uint32_t*)sW1)[idx] = 0u;
    __syncthreads();                                        // pad-zero before scatter
    for (int idx = tid; idx < 27 * 64; idx += 256) {        // W1, linear in memory
        const int k = idx >> 6, h = idx & 63;
        *(_Float16*)(sW1 + h * 64 + (((k >> 3) ^ (h & 3)) << 4) + ((k & 7) << 1)) =
            (_Float16)W1g[idx];
    }
    for (int idx = tid; idx < 64 * 64; idx += 256) {        // W2, Wc, linear
        const int k = idx >> 6, h = idx & 63;
        const int off = h * 128 + ((((k >> 2) ^ ((h & 7) << 1)) << 3)) + ((k & 3) << 1);
        *(_Float16*)(sW2 + off) = (_Float16)W2g[idx];
        *(_Float16*)(sWc + off) = (_Float16)Wcg[idx];
    }
    for (int idx = tid; idx < 192; idx += 256) {            // rgb head rows, linear
        const int kk = idx / 3, c = idx - 3 * kk;
        const _Float16 v = (_Float16)Wrg[idx];
        #pragma unroll
        for (int r = 0; r < 16; ++r) {
            if ((r % 3) == c) {
                const int off = r * 128 + ((((kk >> 2) ^ ((r & 7) << 1)) << 3)) + ((kk & 3) << 1);
                *(_Float16*)(sHC + off) = v;
            }
        }
    }
    if (tid < 64) {
        sB1[tid] = b1g[tid]; sB2[tid] = b2g[tid];
        sWs[tid] = Wsg[tid];
    }
    if (tid == 0) {   // sniff occ dtype: 0=u8, 1=i32, 2=f32
        const int*   oi = (const int*)occ;
        const float* of = (const float*)occ;
        bool i32ok = true, f32ok = true;
        for (int k = 0; k < 64; ++k) {
            if (oi[k] != 0 && oi[k] != 1) i32ok = false;
            const float f = of[k];
            if (!(f == 0.f || f == 1.f)) f32ok = false;
        }
        sKind = i32ok ? 1 : (f32ok ? 2 : 0);
    }
    __syncthreads();

    const int lane = tid & 63;
    const int wid  = tid >> 6;
    const int bat  = wid & 1;         // batch this wave owns
    const int pr   = wid >> 1;        // ray slot within block (0/1)
    const int kind = sKind;
    const int lh = lane & 15, g = lane >> 4;
    const int swz8 = (lh & 7) << 1;

    const float bsV = bsg[0];
    const float br0 = brg[0], br1 = brg[1], br2 = brg[2];

    const int baseStride = (int)(gridDim.x << 1);
    for (int base = (int)(blockIdx.x << 1); base < nrays; base += baseStride) {
        const int ray = base + pr;
        const bool haveRay = ray < nrays;

        float aW = 0.f, aWT = 0.f, aR = 0.f, aG = 0.f, aB = 0.f, Ssum = 0.f;

        if (haveRay) {
            const float ox = rays_o[ray * 3 + 0], oy = rays_o[ray * 3 + 1], oz = rays_o[ray * 3 + 2];
            const float dxv = viewdirs[ray * 3 + 0], dyv = viewdirs[ray * 3 + 1], dzv = viewdirs[ray * 3 + 2];
            const float sdx = fabsf(dxv) < 1e-8f ? 1e-8f : dxv;
            const float sdy = fabsf(dyv) < 1e-8f ? 1e-8f : dyv;
            const float sdz = fabsf(dzv) < 1e-8f ? 1e-8f : dzv;
            const float t1x = (-1.5f - ox) / sdx, t2x = (1.5f - ox) / sdx;
            const float t1y = (-1.5f - oy) / sdy, t2y = (1.5f - oy) / sdy;
            const float t1z = (-1.5f - oz) / sdz, t2z = (1.5f - oz) / sdz;
            const float t_near = fmaxf(fmaxf(fminf(t1x, t2x), fminf(t1y, t2y)),
                                       fmaxf(fminf(t1z, t2z), 0.f));
            const float t_far  = fminf(fminf(fmaxf(t1x, t2x), fmaxf(t1y, t2y)), fmaxf(t1z, t2z));

            // per-ray dir posenc -> sPdB[wid][j] (each wave computes its own copy)
            {
                float ped[15];
                ped[0] = dxv; ped[1] = dyv; ped[2] = dzv;
                const float dc[3] = {dxv, dyv, dzv};
                #pragma unroll
                for (int c = 0; c < 3; ++c) {
                    float s1, c1;
                    __sincosf(dc[c], &s1, &c1);
                    ped[3 + c * 4 + 0] = s1;
                    ped[3 + c * 4 + 1] = 2.f * s1 * c1;
                    ped[3 + c * 4 + 2] = c1;
                    ped[3 + c * 4 + 3] = 1.f - 2.f * s1 * s1;
                }
                float pd = 0.f;
                #pragma unroll
                for (int i = 0; i < 15; ++i) pd += ped[i] * Wdg[i * 64 + lane];
                sPdB[wid][lane] = pd + bcg[lane];
            }

            // ---- own-sample validity + occupancy gather ----
            const float tS = t_near + ((float)((bat << 6) | lane) + 0.5f) * STEPf;
            const bool in_seg = tS < t_far;
            bool valid;
            {
                const float px = ox + dxv * tS, py = oy + dyv * tS, pz = oz + dzv * tS;
                const float cx = (px + 1.5f) * (128.f / 3.f);
                const float cy = (py + 1.5f) * (128.f / 3.f);
                const float cz = (pz + 1.5f) * (128.f / 3.f);
                const bool in_box = (cx >= 0.f) & (cx < 128.f) & (cy >= 0.f) & (cy < 128.f)
                                  & (cz >= 0.f) & (cz < 128.f);
                const int ix = min(max((int)floorf(cx), 0), 127);
                const int iy = min(max((int)floorf(cy), 0), 127);
                const int iz = min(max((int)floorf(cz), 0), 127);
                const int ci = (ix << 14) | (iy << 7) | iz;
                bool occv;
                if (kind == 1)      occv = ((const int*)occ)[ci] != 0;
                else if (kind == 2) occv = ((const float*)occ)[ci] != 0.f;
                else                occv = ((const unsigned char*)occ)[ci] != 0;
                valid = in_seg & in_box & occv;
            }

            if (__ballot(valid) != 0ULL) {
                // ---- posenc in x32-B layout (lane: feats 8g..8g+7, samples 16nt+lh) ----
                f16x8 bx[4];
                #pragma unroll
                for (int nt = 0; nt < 4; ++nt) {
                    const float ts = t_near + ((float)((bat << 6) + (nt << 4) + lh) + 0.5f) * STEPf;
                    const float qx = ox + dxv * ts, qy = oy + dyv * ts, qz = oz + dzv * ts;
                    const float u = (g < 2) ? qx : ((g == 2) ? qy : qz);
                    const float v = (g == 1) ? qy : ((g == 2) ? qz : 0.f);
                    float su1, cu1, sv1, cv1;
                    __sincosf(u, &su1, &cu1);
                    __sincosf(v, &sv1, &cv1);
                    const float su2 = 2.f * su1 * cu1, cu2 = 1.f - 2.f * su1 * su1;
                    const float su4 = 2.f * su2 * cu2, cu4 = 1.f - 2.f * su2 * su2;
                    const float su8 = 2.f * su4 * cu4, cu8 = 1.f - 2.f * su4 * su4;
                    const float sv2 = 2.f * sv1 * cv1, cv2 = 1.f - 2.f * sv1 * sv1;
                    const float sv4 = 2.f * sv2 * cv2, cv4 = 1.f - 2.f * sv2 * sv2;
                    const float sv8 = 2.f * sv4 * cv4;
                    const bool g0 = (g == 0);
                    const float f0 = g0 ? qx : cu2;
                    const float f1 = g0 ? qy : cu4;
                    const float f2 = g0 ? qz : cu8;
                    const float f3 = g0 ? su1 : sv1;
                    const float f4 = g0 ? su2 : sv2;
                    const float f5 = g0 ? su4 : sv4;
                    const float f6 = g0 ? su8 : sv8;
                    const float f7 = g0 ? cu1 : ((g == 3) ? 0.f : cv1);
                    bx[nt] = mk8(pk2(f0, f1), pk2(f2, f3), pk2(f4, f5), pk2(f6, f7));
                }

                // ---- L1 (16x16x32): bias as C ----
                f16x4 bh1[4][4];
                #pragma unroll
                for (int mt = 0; mt < 4; ++mt) {
                    const f32x4 bf = *(const f32x4*)&sB1[16 * mt + 4 * g];
                    const f16x8 a = *(const f16x8*)(sW1 + (16 * mt + lh) * 64 + ((g ^ (lh & 3)) << 4));
                    #pragma unroll
                    for (int nt = 0; nt < 4; ++nt) {
                        f32x4 c = __builtin_amdgcn_mfma_f32_16x16x32_f16(a, bx[nt], bf, 0, 0, 0);
                        bh1[mt][nt] = pkh(c);   // D rows 4g+r == B k 4g+e for k-step mt
                    }
                }
                // ---- L2 (4 x 16x16x16 per tile) + fused VALU sigma partials ----
                f16x4 bh2[4][4];
                float sp[4] = {0.f, 0.f, 0.f, 0.f};
                #pragma unroll
                for (int mt = 0; mt < 4; ++mt) {
                    const int row = (16 * mt + lh) * 128;
                    f16x4 a0 = *(const f16x4*)(sW2 + row + (((0 + g) ^ swz8) << 3));
                    f16x4 a1 = *(const f16x4*)(sW2 + row + (((4 + g) ^ swz8) << 3));
                    f16x4 a2 = *(const f16x4*)(sW2 + row + (((8 + g) ^ swz8) << 3));
                    f16x4 a3 = *(const f16x4*)(sW2 + row + (((12 + g) ^ swz8) << 3));
                    const f32x4 bf = *(const f32x4*)&sB2[16 * mt + 4 * g];
                    const f32x4 ws = *(const f32x4*)&sWs[16 * mt + 4 * g];
                    #pragma unroll
                    for (int nt = 0; nt < 4; ++nt) {
                        f32x4 c = __builtin_amdgcn_mfma_f32_16x16x16f16(a0, bh1[0][nt], bf, 0, 0, 0);
                        c = __builtin_amdgcn_mfma_f32_16x16x16f16(a1, bh1[1][nt], c, 0, 0, 0);
                        c = __builtin_amdgcn_mfma_f32_16x16x16f16(a2, bh1[2][nt], c, 0, 0, 0);
                        c = __builtin_amdgcn_mfma_f32_16x16x16f16(a3, bh1[3][nt], c, 0, 0, 0);
                        const float r0 = fmaxf(c[0], 0.f), r1 = fmaxf(c[1], 0.f);
                        const float r2 = fmaxf(c[2], 0.f), r3 = fmaxf(c[3], 0.f);
                        sp[nt] += ws[0] * r0 + ws[1] * r1 + ws[2] * r2 + ws[3] * r3;
                        uint2 u; u.x = pk2(r0, r1); u.y = pk2(r2, r3);
                        bh2[mt][nt] = __builtin_bit_cast(f16x4, u);
                    }
                }
                // ---- Wc layer (C = pd + bc) ----
                f16x4 bgf[4][4];
                #pragma unroll
                for (int mt = 0; mt < 4; ++mt) {
                    const int row = (16 * mt + lh) * 128;
                    f16x4 a0 = *(const f16x4*)(sWc + row + (((0 + g) ^ swz8) << 3));
                    f16x4 a1 = *(const f16x4*)(sWc + row + (((4 + g) ^ swz8) << 3));
                    f16x4 a2 = *(const f16x4*)(sWc + row + (((8 + g) ^ swz8) << 3));
                    f16x4 a3 = *(const f16x4*)(sWc + row + (((12 + g) ^ swz8) << 3));
                    const f32x4 pdf = *(const f32x4*)&sPdB[wid][16 * mt + 4 * g];
                    #pragma unroll
                    for (int nt = 0; nt < 4; ++nt) {
                        f32x4 c = __builtin_amdgcn_mfma_f32_16x16x16f16(a0, bh2[0][nt], pdf, 0, 0, 0);
                        c = __builtin_amdgcn_mfma_f32_16x16x16f16(a1, bh2[1][nt], c, 0, 0, 0);
                        c = __builtin_amdgcn_mfma_f32_16x16x16f16(a2, bh2[2][nt], c, 0, 0, 0);
                        c = __builtin_amdgcn_mfma_f32_16x16x16f16(a3, bh2[3][nt], c, 0, 0, 0);
                        bgf[mt][nt] = pkh(c);
                    }
                }
                // ---- rgb head: A row r = Wr[.][r%3] -> every lane holds all 3 colors ----
                f32x4 accC[4];
                #pragma unroll
                for (int ks = 0; ks < 4; ++ks) {
                    const f16x4 aC = *(const f16x4*)(sHC + lh * 128 + (((4 * ks + g) ^ swz8) << 3));
                    #pragma unroll
                    for (int nt = 0; nt < 4; ++nt) {
                        f32x4 c = (ks == 0) ? f32x4{0.f, 0.f, 0.f, 0.f} : accC[nt];
                        accC[nt] = __builtin_amdgcn_mfma_f32_16x16x16f16(aC, bgf[ks][nt], c, 0, 0, 0);
                    }
                }
                // ---- sigma reduce over g-groups + own-sample selects ----
                #pragma unroll
                for (int nt = 0; nt < 4; ++nt) {
                    sp[nt] += __shfl_xor(sp[nt], 16);
                    sp[nt] += __shfl_xor(sp[nt], 32);
                }
                const float sraw = (g == 0) ? sp[0] : (g == 1) ? sp[1]
                                 : (g == 2) ? sp[2] : sp[3];
                const float crS  = (g == 0) ? accC[0][0] : (g == 1) ? accC[1][2]
                                 : (g == 2) ? accC[2][1] : accC[3][0];
                const float cgS  = (g == 0) ? accC[0][1] : (g == 1) ? accC[1][0]
                                 : (g == 2) ? accC[2][2] : accC[3][1];
                const float cbS  = (g == 0) ? accC[0][2] : (g == 1) ? accC[1][1]
                                 : (g == 2) ? accC[2][0] : accC[3][2];

                const float sigma = valid ? fmaxf(sraw + bsV, 0.f) : 0.f;
                const float rC = 1.f / (1.f + __expf(-(crS + br0)));
                const float gC = 1.f / (1.f + __expf(-(cgS + br1)));
                const float bC = 1.f / (1.f + __expf(-(cbS + br2)));

                // ---- compositing with carry = 0 (exact factoring: see header) ----
                const float sdelta = sigma * STEPf;
                float scan = sdelta;
                #pragma unroll
                for (int off = 1; off < 64; off <<= 1) {
                    const float n = __shfl_up(scan, off);
                    if (lane >= off) scan += n;
                }
                const float T     = __expf(-(scan - sdelta));
                const float alpha = 1.f - __expf(-sdelta);
                const float w = T * alpha;
                aW  = w;
                aWT = w * tS;
                aR  = w * rC;
                aG  = w * gC;
                aB  = w * bC;
                Ssum = __shfl(scan, 63);
            }
        }

        // ---- wave-reduce the five accumulators ----
        #pragma unroll
        for (int off = 32; off; off >>= 1) {
            aW  += __shfl_xor(aW,  off);
            aWT += __shfl_xor(aWT, off);
            aR  += __shfl_xor(aR,  off);
            aG  += __shfl_xor(aG,  off);
            aB  += __shfl_xor(aB,  off);
        }
        if (lane == 0) {
            sRed[wid][0] = aW;  sRed[wid][1] = aWT; sRed[wid][2] = aR;
            sRed[wid][3] = aG;  sRed[wid][4] = aB;  sRed[wid][5] = Ssum;
        }
        __syncthreads();
        if (haveRay && bat == 0 && lane == 0) {
            const float f = __expf(-Ssum);           // exp(-S0): batch-1 scale
            const float W1a = aW  + f * sRed[wid | 1][0];
            const float WTa = aWT + f * sRed[wid | 1][1];
            const float Ra  = aR  + f * sRed[wid | 1][2];
            const float Ga  = aG  + f * sRed[wid | 1][3];
            const float Ba  = aB  + f * sRed[wid | 1][4];
            const float bg_ = 1.f - W1a;
            out[ray * 3 + 0] = Ra + bg_;
            out[ray * 3 + 1] = Ga + bg_;
            out[ray * 3 + 2] = Ba + bg_;
            out[3 * nrays + ray] = WTa;
            out[4 * nrays + ray] = W1a;
        }
        __syncthreads();   // protect sRed/sPdB reuse next iteration
    }
}

extern "C" void kernel_launch(void* const* d_in, const int* in_sizes, int n_in,
                              void* d_out, int out_size, void* d_ws, size_t ws_size,
                              hipStream_t stream) {
    const float* rays_o   = (const float*)d_in[0];
    const float* viewdirs = (const float*)d_in[1];
    const void*  occ      = (const void*) d_in[2];
    const float* W1 = (const float*)d_in[3];
    const float* b1 = (const float*)d_in[4];
    const float* W2 = (const float*)d_in[5];
    const float* b2 = (const float*)d_in[6];
    const float* Ws = (const float*)d_in[7];
    const float* bs = (const float*)d_in[8];
    const float* Wc = (const float*)d_in[9];
    const float* Wd = (const float*)d_in[10];
    const float* bc = (const float*)d_in[11];
    const float* Wr = (const float*)d_in[12];
    const float* br = (const float*)d_in[13];
    float* out = (float*)d_out;

    const int nrays = in_sizes[0] / 3;
    int nblocks = 1024;                      // persistent: 4 blocks/CU, grid-stride
    const int needed = (nrays + 1) / 2;      // 2 rays per block
    if (needed < nblocks) nblocks = needed;

    nerf_mfma<<<nblocks, 256, 0, stream>>>(rays_o, viewdirs, occ,
                                           W1, b1, W2, b2, Ws, bs, Wc, Wd, bc, Wr, br,
                                           out, nrays);
}